// Round 9
// baseline (753.648 us; speedup 1.0000x reference)
//
#include <hip/hip_runtime.h>
#include <hip/hip_bf16.h>

#define D_IN 768
#define D_HID 256

typedef __attribute__((ext_vector_type(8))) short short8;
typedef __attribute__((ext_vector_type(4))) float f32x4;

__device__ inline float b2f(unsigned short u) {
    unsigned x = ((unsigned)u) << 16;
    union { unsigned u; float f; } c; c.u = x; return c.f;
}
__device__ inline unsigned short f2b(float v) {
    __hip_bfloat16 h = __float2bfloat16(v);
    return *(unsigned short*)&h;
}

__device__ inline void gload_lds16(const void* g, void* l) {
    __builtin_amdgcn_global_load_lds(
        (const __attribute__((address_space(1))) unsigned int*)g,
        (__attribute__((address_space(3))) unsigned int*)l, 16, 0, 0);
}

// ---------------- CSR build ----------------

__global__ void k_count(const int* __restrict__ dst, int* __restrict__ deg, int E) {
    int i = blockIdx.x * 256 + threadIdx.x;
    if (i < E) atomicAdd(&deg[dst[i]], 1);
}

__global__ void k_dinv(const int* __restrict__ deg, float* __restrict__ dinv, int N) {
    int i = blockIdx.x * 256 + threadIdx.x;
    if (i < N) dinv[i] = rsqrtf((float)deg[i] + 1.0f);
}

__global__ __launch_bounds__(1024) void k_scan(const int* __restrict__ deg,
                                               int* __restrict__ row_ptr, int N) {
    __shared__ int wsum[16];
    __shared__ int carry_s;
    int t = threadIdx.x;
    int lane = t & 63, wid = t >> 6;
    if (t == 0) carry_s = 0;
    __syncthreads();
    for (int base = 0; base < N; base += 1024) {
        int i = base + t;
        int v = (i < N) ? deg[i] : 0;
        int s = v;
        #pragma unroll
        for (int d = 1; d < 64; d <<= 1) {
            int tmp = __shfl_up(s, d);
            if (lane >= d) s += tmp;
        }
        if (lane == 63) wsum[wid] = s;
        __syncthreads();
        if (wid == 0 && lane < 16) {
            int ws = wsum[lane];
            #pragma unroll
            for (int d = 1; d < 16; d <<= 1) {
                int tmp = __shfl_up(ws, d);
                if (lane >= d) ws += tmp;
            }
            wsum[lane] = ws;
        }
        __syncthreads();
        int carry = carry_s;
        int woff = (wid > 0) ? wsum[wid - 1] : 0;
        if (i < N) row_ptr[i] = carry + woff + s - v;
        __syncthreads();
        if (t == 0) carry_s = carry + wsum[15];
        __syncthreads();
    }
    if (t == 0) row_ptr[N] = carry_s;
}

__global__ void k_fill(const int* __restrict__ src, const int* __restrict__ dst,
                       const int* __restrict__ row_ptr, int* __restrict__ wptr,
                       int* __restrict__ csr_src, int E) {
    int i = blockIdx.x * 256 + threadIdx.x;
    if (i < E) {
        int d = dst[i];
        int w = atomicAdd(&wptr[d], 1);
        csr_src[row_ptr[d] + w] = src[i];
    }
}

__global__ void k_bounds(const int* __restrict__ batch, int* __restrict__ cnt,
                         int* __restrict__ offg, int N, int G) {
    int g = threadIdx.x;
    if (g >= G) return;
    auto lower = [&](int key) {
        int lo = 0, hi = N;
        while (lo < hi) {
            int mid = (lo + hi) >> 1;
            if (batch[mid] < key) lo = mid + 1; else hi = mid;
        }
        return lo;
    };
    int lo = lower(g);
    int hi = lower(g + 1);
    offg[g] = lo;
    cnt[g] = hi - lo;
}

// ---------------- head-weight precompute: Wc = W3 @ Wl, bc = b3 @ Wl + bl -------
__global__ __launch_bounds__(256) void k_wc(const float* __restrict__ W3,
                                            const float* __restrict__ Wl,
                                            float* __restrict__ Wc) {
    __shared__ float w3s[16][256];
    int t = threadIdx.x;
    int cx = blockIdx.x, iq = blockIdx.y;
    #pragma unroll
    for (int r = 0; r < 16; ++r)
        w3s[r][t] = W3[(size_t)(iq * 16 + r) * 256 + t];
    __syncthreads();
    int c = cx * 256 + t;
    float acc[16];
    #pragma unroll
    for (int i = 0; i < 16; ++i) acc[i] = 0.f;
    for (int m = 0; m < 256; ++m) {
        float wl = Wl[(size_t)m * 768 + c];
        #pragma unroll
        for (int i = 0; i < 16; ++i) acc[i] = fmaf(w3s[i][m], wl, acc[i]);
    }
    #pragma unroll
    for (int i = 0; i < 16; ++i)
        Wc[(size_t)(iq * 16 + i) * 768 + c] = acc[i];
}

__global__ __launch_bounds__(256) void k_bc(const float* __restrict__ b3,
                                            const float* __restrict__ Wl,
                                            const float* __restrict__ bl,
                                            float* __restrict__ bc) {
    __shared__ float b3s[256];
    int t = threadIdx.x;
    b3s[t] = b3[t];
    __syncthreads();
    int c = blockIdx.x * 256 + t;
    float acc = bl[c];
    for (int m = 0; m < 256; ++m) acc = fmaf(b3s[m], Wl[(size_t)m * 768 + c], acc);
    bc[c] = acc;
}

// ---------------- B prep: W fp32 [KA][256] -> per-chunk fragment-swizzled hi/lo --
__global__ void k_prep_B(const float* __restrict__ W, short* __restrict__ Bp, int KA) {
    int t = blockIdx.x * 256 + threadIdx.x;
    if (t >= KA * 256) return;
    int k = t >> 8, n = t & 255;
    float v = W[(size_t)k * 256 + n];
    unsigned short h = f2b(v);
    unsigned short l = f2b(v - b2f(h));
    int c = k >> 5, q = (k >> 3) & 3, j = k & 7;
    int tile = n >> 4, ln = n & 15;
    size_t base = (size_t)c * 16384 + (size_t)(tile * 4 + q) * 128 + ln * 8 + j;
    Bp[base] = (short)h;            // f=0
    Bp[base + 8192] = (short)l;     // f=1 (16*4*128 = 8192)
}

// ---------------- MFMA GEMM v7: col-split 128x128 tile + A register prefetch ----
// grid (row_tiles, 2); 512 thr = 8 waves (4 row-groups x 2 col-groups).
// Wave (wr2,wc2): rows [bm+wr2*32,+32) (2 strips), cols [bn+wc2*64,+64) (4 tt).
// acc = 32 AGPR (half of v4) -> depth-1 A register prefetch fits under the
// 128-reg / 4-waves-per-SIMD cap. B-chunk 16 KB, dbuf 32 KB LDS -> 2 blocks/CU.
// A is read twice total (once per col-half; L3-resident). Numerics identical.
// MODE 1: A fp32, 3 terms. MODE 2: A bf16 exact, 2 terms.
template <int MODE>
__global__ __launch_bounds__(512, 4) void k_gemm7(const void* __restrict__ Av,
                                                  const short* __restrict__ Bp,
                                                  unsigned short* __restrict__ C,
                                                  int M) {
    constexpr int KA = (MODE == 1) ? D_IN : D_HID;
    constexpr int NCH = KA / 32;
    __shared__ short Bs[2][8192];  // 2 x 16 KB

    int t = threadIdx.x;
    int lane = t & 63, w = t >> 6;
    int wr2 = w >> 1, wc2 = w & 1;
    int ln = lane & 15, q = lane >> 4;
    int bm = blockIdx.x * 128;
    int bn = blockIdx.y * 128;
    int TB = blockIdx.y * 8;          // global 16-col tile base for this col-half

    const char* Abase[2];
    #pragma unroll
    for (int s = 0; s < 2; ++s) {
        int rr = bm + wr2 * 32 + s * 16 + ln;
        rr = (rr < M) ? rr : (M - 1);
        Abase[s] = (const char*)Av + (size_t)rr * KA * ((MODE == 1) ? 4 : 2);
    }

    f32x4 acc[2][4];
    #pragma unroll
    for (int s = 0; s < 2; ++s)
        #pragma unroll
        for (int tt = 0; tt < 4; ++tt) acc[s][tt] = (f32x4){0.f, 0.f, 0.f, 0.f};

    // stage chunk c's 8 hi tiles + 8 lo tiles (this col-half) into Bs[pb]
    auto stage = [&](int c, int pb) {
        gload_lds16(Bp + (size_t)c * 16384 + (size_t)(TB + w) * 512 + lane * 8,
                    &Bs[pb][w * 512]);
        gload_lds16(Bp + (size_t)c * 16384 + 8192 + (size_t)(TB + w) * 512 + lane * 8,
                    &Bs[pb][4096 + w * 512]);
    };

    stage(0, 0);

    // preload A chunk 0 (overlaps with stage 0; barrier below drains both)
    f32x4 cur0[2], cur1[2];
    short8 curb[2];
    #pragma unroll
    for (int s = 0; s < 2; ++s) {
        if (MODE == 1) {
            const float* Af = (const float*)(Abase[s]) + q * 8;
            cur0[s] = *(const f32x4*)Af;
            cur1[s] = *(const f32x4*)(Af + 4);
        } else {
            curb[s] = *(const short8*)((const unsigned short*)(Abase[s]) + q * 8);
        }
    }
    __syncthreads();

    for (int c = 0; c < NCH; ++c) {
        int pb = c & 1;
        bool more = (c + 1 < NCH);
        if (more) stage(c + 1, pb ^ 1);

        // depth-1 A prefetch: issue next chunk's loads now; consumed next
        // iteration, so this chunk's convert+MFMA hides their latency.
        f32x4 nxt0[2], nxt1[2];
        short8 nxtb[2];
        if (more) {
            #pragma unroll
            for (int s = 0; s < 2; ++s) {
                if (MODE == 1) {
                    const float* Af = (const float*)(Abase[s]) + (c + 1) * 32 + q * 8;
                    nxt0[s] = *(const f32x4*)Af;
                    nxt1[s] = *(const f32x4*)(Af + 4);
                } else {
                    nxtb[s] = *(const short8*)((const unsigned short*)(Abase[s]) + (c + 1) * 32 + q * 8);
                }
            }
        }

        // convert current A chunk
        short8 a_hi[2], a_lo[2];
        #pragma unroll
        for (int s = 0; s < 2; ++s) {
            if (MODE == 1) {
                float vv[8] = {cur0[s][0], cur0[s][1], cur0[s][2], cur0[s][3],
                               cur1[s][0], cur1[s][1], cur1[s][2], cur1[s][3]};
                #pragma unroll
                for (int j = 0; j < 8; ++j) {
                    unsigned short h = f2b(vv[j]);
                    a_hi[s][j] = (short)h;
                    a_lo[s][j] = (short)f2b(vv[j] - b2f(h));
                }
            } else {
                a_hi[s] = curb[s];
            }
        }

        #pragma unroll
        for (int tt = 0; tt < 4; ++tt) {
            const short* bp = &Bs[pb][(size_t)(wc2 * 4 + tt) * 512 + q * 128 + ln * 8];
            short8 bh = *(const short8*)bp;
            short8 bl2 = *(const short8*)(bp + 4096);
            #pragma unroll
            for (int s = 0; s < 2; ++s) {
                acc[s][tt] = __builtin_amdgcn_mfma_f32_16x16x32_bf16(a_hi[s], bh, acc[s][tt], 0, 0, 0);
                if (MODE == 1)
                    acc[s][tt] = __builtin_amdgcn_mfma_f32_16x16x32_bf16(a_lo[s], bh, acc[s][tt], 0, 0, 0);
                acc[s][tt] = __builtin_amdgcn_mfma_f32_16x16x32_bf16(a_hi[s], bl2, acc[s][tt], 0, 0, 0);
            }
        }
        __syncthreads();

        if (more) {
            #pragma unroll
            for (int s = 0; s < 2; ++s) {
                if (MODE == 1) { cur0[s] = nxt0[s]; cur1[s] = nxt1[s]; }
                else           { curb[s] = nxtb[s]; }
            }
        }
    }

    // C/D: row = bm + wr2*32 + s*16 + q*4 + r, col = bn + wc2*64 + tt*16 + ln
    #pragma unroll
    for (int s = 0; s < 2; ++s)
        #pragma unroll
        for (int tt = 0; tt < 4; ++tt)
            #pragma unroll
            for (int r = 0; r < 4; ++r) {
                int row = bm + wr2 * 32 + s * 16 + q * 4 + r;
                if (row < M)
                    C[(size_t)row * 256 + bn + wc2 * 64 + tt * 16 + ln] = f2b(acc[s][tt][r]);
            }
}

// ---------------- aggregation: lane-parallel index prefetch + shfl-fed gathers ---
// At the random-gather byte floor (3 structurally different schemes all null).
template <int RELU, int OUTBF>
__global__ __launch_bounds__(256) void k_agg(const unsigned short* __restrict__ hin,
                                             void* __restrict__ hout,
                                             const int* __restrict__ row_ptr,
                                             const int* __restrict__ csr_src,
                                             const float* __restrict__ dinv,
                                             const float* __restrict__ bias, int N) {
    int w = threadIdx.x >> 6;
    int lane = threadIdx.x & 63;
    int row = blockIdx.x * 4 + w;
    if (row >= N) return;
    int half = lane >> 5;
    int hl = lane & 31;
    int c8 = hl * 8;

    int2 se = *(const int2*)&row_ptr[row];
    int s = se.x, e = se.y;

    float di = dinv[row];
    short8 vs = *(const short8*)&hin[(size_t)row * 256 + c8];
    float4 bb0 = *(const float4*)&bias[c8];
    float4 bb1 = *(const float4*)&bias[c8 + 4];

    float acc[8];
    #pragma unroll
    for (int ch = 0; ch < 8; ++ch) acc[ch] = 0.f;

    for (int base = s; base < e; base += 64) {
        int cnt = e - base;
        if (cnt > 64) cnt = 64;
        int gidx = base + lane;
        if (gidx >= e) gidx = e - 1;
        int myu = csr_src[gidx];
        float mydv = dinv[myu];

        int p = 0;
        for (; p + 8 <= cnt; p += 8) {
            int u[4];
            float dv[4];
            short8 v[4];
            #pragma unroll
            for (int qq = 0; qq < 4; ++qq) {
                u[qq]  = __shfl(myu,  p + 2 * qq + half);
                dv[qq] = __shfl(mydv, p + 2 * qq + half);
            }
            #pragma unroll
            for (int qq = 0; qq < 4; ++qq) v[qq] = *(const short8*)&hin[(size_t)u[qq] * 256 + c8];
            #pragma unroll
            for (int qq = 0; qq < 4; ++qq)
                #pragma unroll
                for (int ch = 0; ch < 8; ++ch)
                    acc[ch] += dv[qq] * b2f((unsigned short)v[qq][ch]);
        }
        for (; p + 2 <= cnt; p += 2) {
            int u  = __shfl(myu,  p + half);
            float dv = __shfl(mydv, p + half);
            short8 v = *(const short8*)&hin[(size_t)u * 256 + c8];
            #pragma unroll
            for (int ch = 0; ch < 8; ++ch) acc[ch] += dv * b2f((unsigned short)v[ch]);
        }
        if (p < cnt) {
            int u = __shfl(myu, p);
            float dv = half ? 0.f : __shfl(mydv, p);
            short8 v = *(const short8*)&hin[(size_t)u * 256 + c8];
            #pragma unroll
            for (int ch = 0; ch < 8; ++ch) acc[ch] += dv * b2f((unsigned short)v[ch]);
        }
    }

    #pragma unroll
    for (int ch = 0; ch < 8; ++ch) acc[ch] += __shfl_xor(acc[ch], 32);

    float dii = di * di;
    float r[8];
    #pragma unroll
    for (int ch = 0; ch < 8; ++ch) {
        float b = (ch < 4) ? ((ch == 0) ? bb0.x : (ch == 1) ? bb0.y : (ch == 2) ? bb0.z : bb0.w)
                           : ((ch == 4) ? bb1.x : (ch == 5) ? bb1.y : (ch == 6) ? bb1.z : bb1.w);
        r[ch] = acc[ch] * di + dii * b2f((unsigned short)vs[ch]) + b;
        if (RELU) r[ch] = fmaxf(r[ch], 0.f);
    }

    float r0 = half ? r[4] : r[0];
    float r1 = half ? r[5] : r[1];
    float r2 = half ? r[6] : r[2];
    float r3 = half ? r[7] : r[3];
    int cofs = c8 + half * 4;

    if (OUTBF) {
        ushort4 o;
        o.x = f2b(r0); o.y = f2b(r1); o.z = f2b(r2); o.w = f2b(r3);
        *(ushort4*)((unsigned short*)hout + (size_t)row * 256 + cofs) = o;
    } else {
        *(float4*)((float*)hout + (size_t)row * 256 + cofs) = make_float4(r0, r1, r2, r3);
    }
}

// ---------------- pool ----------------
__global__ __launch_bounds__(256) void k_pool(const float* __restrict__ h,
                                              const int* __restrict__ cnt,
                                              const int* __restrict__ offg,
                                              float* __restrict__ g) {
    int gi = blockIdx.x, slice = blockIdx.y;
    int c = threadIdx.x;
    int start = offg[gi], n = cnt[gi];
    int per = (n + (int)gridDim.y - 1) / (int)gridDim.y;
    int r0 = slice * per;
    int r1 = min(n, r0 + per);
    float acc = 0.f;
    for (int r = r0; r < r1; ++r) acc += h[(size_t)(start + r) * D_HID + c];
    if (r1 > r0) atomicAdd(&g[gi * D_HID + c], acc);
}

// ---------------- head: out[g] = (gbuf[g]/cnt) @ Wc + bc ----------------
__global__ __launch_bounds__(256) void k_final(const float* __restrict__ g,
                                               const int* __restrict__ cnt,
                                               const float* __restrict__ Wc,
                                               const float* __restrict__ bc,
                                               float* __restrict__ out) {
    __shared__ float gs[D_HID];
    int t = threadIdx.x;
    int gi = blockIdx.y;
    int c = blockIdx.x * 256 + t;
    float inv = 1.0f / (float)max(cnt[gi], 1);
    gs[t] = g[gi * D_HID + t] * inv;
    __syncthreads();
    float acc = bc[c];
    #pragma unroll 8
    for (int k = 0; k < D_HID; ++k) acc = fmaf(gs[k], Wc[(size_t)k * D_IN + c], acc);
    out[(size_t)gi * D_IN + c] = acc;
}

// ---------------- launch ----------------

extern "C" void kernel_launch(void* const* d_in, const int* in_sizes, int n_in,
                              void* d_out, int out_size, void* d_ws, size_t ws_size,
                              hipStream_t stream) {
    const float* x     = (const float*)d_in[0];
    const int*   ei    = (const int*)d_in[1];
    const int*   batch = (const int*)d_in[2];
    const float* W1 = (const float*)d_in[3];
    const float* b1 = (const float*)d_in[4];
    const float* W2 = (const float*)d_in[5];
    const float* b2 = (const float*)d_in[6];
    const float* W3 = (const float*)d_in[7];
    const float* b3 = (const float*)d_in[8];
    const float* Wl = (const float*)d_in[9];
    const float* bl = (const float*)d_in[10];
    float* out = (float*)d_out;

    int N = in_sizes[2];
    int E = in_sizes[1] / 2;
    int G = out_size / D_IN;
    const int* srcp = ei;
    const int* dstp = ei + E;

    char* ws = (char*)d_ws;
    size_t o = 0;
    auto alloc = [&](size_t bytes) -> char* {
        char* p = ws + o;
        o += (bytes + 255) & ~(size_t)255;
        return p;
    };
    int*   deg     = (int*)alloc((size_t)N * 4);
    int*   wptr    = (int*)alloc((size_t)N * 4);
    int*   row_ptr = (int*)alloc((size_t)(N + 1) * 4);
    int*   cnt     = (int*)alloc((size_t)G * 4);
    int*   offg    = (int*)alloc((size_t)G * 4);
    int*   csr_src = (int*)alloc((size_t)E * 4);
    float* dinv    = (float*)alloc((size_t)N * 4);
    float* gbuf    = (float*)alloc((size_t)G * D_HID * 4);
    float* zbias   = (float*)alloc((size_t)D_HID * 4);
    float* Wc      = (float*)alloc((size_t)D_HID * D_IN * 4);
    float* bc      = (float*)alloc((size_t)D_IN * 4);
    unsigned short* hG  = (unsigned short*)alloc((size_t)N * D_HID * 2); // GEMM out (bf16)
    unsigned short* hA2 = (unsigned short*)alloc((size_t)N * D_HID * 2); // agg out L1/L2 (bf16)
    float* hF      = (float*)alloc((size_t)N * D_HID * 4);               // agg out L3 (fp32)
    short* Bp1     = (short*)alloc((size_t)(D_IN / 32) * 16384 * 2);
    short* Bp2     = (short*)alloc((size_t)(D_HID / 32) * 16384 * 2);

    hipMemsetAsync(deg, 0, (size_t)N * 4, stream);
    hipMemsetAsync(wptr, 0, (size_t)N * 4, stream);
    hipMemsetAsync(gbuf, 0, (size_t)G * D_HID * 4, stream);
    hipMemsetAsync(zbias, 0, (size_t)D_HID * 4, stream);

    int gE = (E + 255) / 256;
    int gN = (N + 255) / 256;

    k_count<<<gE, 256, 0, stream>>>(dstp, deg, E);
    k_dinv<<<gN, 256, 0, stream>>>(deg, dinv, N);
    k_scan<<<1, 1024, 0, stream>>>(deg, row_ptr, N);
    k_fill<<<gE, 256, 0, stream>>>(srcp, dstp, row_ptr, wptr, csr_src, E);
    k_bounds<<<1, 64, 0, stream>>>(batch, cnt, offg, N, G);

    k_prep_B<<<D_IN, 256, 0, stream>>>(W1, Bp1, D_IN);
    k_prep_B<<<D_HID, 256, 0, stream>>>(W2, Bp2, D_HID);
    dim3 wc_grid(3, 16);
    k_wc<<<wc_grid, 256, 0, stream>>>(W3, Wl, Wc);
    k_bc<<<3, 256, 0, stream>>>(b3, Wl, bl, bc);

    dim3 gemm_grid((N + 127) / 128, 2);
    int agg_grid = (N + 3) / 4;

    // layer 1 (fp32 A, 3-term fused)
    k_gemm7<1><<<gemm_grid, 512, 0, stream>>>(x, Bp1, hG, N);
    k_agg<1, 1><<<agg_grid, 256, 0, stream>>>(hG, hA2, row_ptr, csr_src, dinv, b1, N);
    // layer 2 (bf16 A exact, 2-term)
    k_gemm7<2><<<gemm_grid, 512, 0, stream>>>(hA2, Bp2, hG, N);
    k_agg<1, 1><<<agg_grid, 256, 0, stream>>>(hG, hA2, row_ptr, csr_src, dinv, b2, N);
    // layer 3: aggregate H2 directly (W3 folded into head via Wc = W3@Wl)
    k_agg<0, 0><<<agg_grid, 256, 0, stream>>>(hA2, hF, row_ptr, csr_src, dinv, zbias, N);

    // pool + head
    dim3 pool_grid(G, 8);
    k_pool<<<pool_grid, 256, 0, stream>>>(hF, cnt, offg, gbuf);
    dim3 fin_grid(D_IN / 256, G);
    k_final<<<fin_grid, 256, 0, stream>>>(gbuf, cnt, Wc, bc, out);
}

// Round 11
// 729.394 us; speedup vs baseline: 1.0333x; 1.0333x over previous
//
#include <hip/hip_runtime.h>
#include <hip/hip_bf16.h>

#define D_IN 768
#define D_HID 256

typedef __attribute__((ext_vector_type(8))) short short8;
typedef __attribute__((ext_vector_type(4))) float f32x4;

__device__ inline float b2f(unsigned short u) {
    unsigned x = ((unsigned)u) << 16;
    union { unsigned u; float f; } c; c.u = x; return c.f;
}
__device__ inline unsigned short f2b(float v) {
    __hip_bfloat16 h = __float2bfloat16(v);
    return *(unsigned short*)&h;
}

__device__ inline void gload_lds16(const void* g, void* l) {
    __builtin_amdgcn_global_load_lds(
        (const __attribute__((address_space(1))) unsigned int*)g,
        (__attribute__((address_space(3))) unsigned int*)l, 16, 0, 0);
}

// ---------------- CSR build ----------------

__global__ void k_count(const int* __restrict__ dst, int* __restrict__ deg, int E) {
    int i = blockIdx.x * 256 + threadIdx.x;
    if (i < E) atomicAdd(&deg[dst[i]], 1);
}

__global__ void k_dinv(const int* __restrict__ deg, float* __restrict__ dinv, int N) {
    int i = blockIdx.x * 256 + threadIdx.x;
    if (i < N) dinv[i] = rsqrtf((float)deg[i] + 1.0f);
}

__global__ __launch_bounds__(1024) void k_scan(const int* __restrict__ deg,
                                               int* __restrict__ row_ptr, int N) {
    __shared__ int wsum[16];
    __shared__ int carry_s;
    int t = threadIdx.x;
    int lane = t & 63, wid = t >> 6;
    if (t == 0) carry_s = 0;
    __syncthreads();
    for (int base = 0; base < N; base += 1024) {
        int i = base + t;
        int v = (i < N) ? deg[i] : 0;
        int s = v;
        #pragma unroll
        for (int d = 1; d < 64; d <<= 1) {
            int tmp = __shfl_up(s, d);
            if (lane >= d) s += tmp;
        }
        if (lane == 63) wsum[wid] = s;
        __syncthreads();
        if (wid == 0 && lane < 16) {
            int ws = wsum[lane];
            #pragma unroll
            for (int d = 1; d < 16; d <<= 1) {
                int tmp = __shfl_up(ws, d);
                if (lane >= d) ws += tmp;
            }
            wsum[lane] = ws;
        }
        __syncthreads();
        int carry = carry_s;
        int woff = (wid > 0) ? wsum[wid - 1] : 0;
        if (i < N) row_ptr[i] = carry + woff + s - v;
        __syncthreads();
        if (t == 0) carry_s = carry + wsum[15];
        __syncthreads();
    }
    if (t == 0) row_ptr[N] = carry_s;
}

__global__ void k_fill(const int* __restrict__ src, const int* __restrict__ dst,
                       const int* __restrict__ row_ptr, int* __restrict__ wptr,
                       int* __restrict__ csr_src, int E) {
    int i = blockIdx.x * 256 + threadIdx.x;
    if (i < E) {
        int d = dst[i];
        int w = atomicAdd(&wptr[d], 1);
        csr_src[row_ptr[d] + w] = src[i];
    }
}

__global__ void k_bounds(const int* __restrict__ batch, int* __restrict__ cnt,
                         int* __restrict__ offg, int N, int G) {
    int g = threadIdx.x;
    if (g >= G) return;
    auto lower = [&](int key) {
        int lo = 0, hi = N;
        while (lo < hi) {
            int mid = (lo + hi) >> 1;
            if (batch[mid] < key) lo = mid + 1; else hi = mid;
        }
        return lo;
    };
    int lo = lower(g);
    int hi = lower(g + 1);
    offg[g] = lo;
    cnt[g] = hi - lo;
}

// ---------------- B prep: W fp32 [KA][256] -> per-chunk fragment-swizzled hi/lo --
__global__ void k_prep_B(const float* __restrict__ W, short* __restrict__ Bp, int KA) {
    int t = blockIdx.x * 256 + threadIdx.x;
    if (t >= KA * 256) return;
    int k = t >> 8, n = t & 255;
    float v = W[(size_t)k * 256 + n];
    unsigned short h = f2b(v);
    unsigned short l = f2b(v - b2f(h));
    int c = k >> 5, q = (k >> 3) & 3, j = k & 7;
    int tile = n >> 4, ln = n & 15;
    size_t base = (size_t)c * 16384 + (size_t)(tile * 4 + q) * 128 + ln * 8 + j;
    Bp[base] = (short)h;            // f=0
    Bp[base + 8192] = (short)l;     // f=1 (16*4*128 = 8192)
}

// ---------------- MFMA GEMM v7 (layer 1): col-split 128x128 tile (R9: 139us) ----
// grid (row_tiles, 2); 512 thr = 8 waves (4 row-groups x 2 col-groups).
template <int MODE>
__global__ __launch_bounds__(512, 4) void k_gemm7(const void* __restrict__ Av,
                                                  const short* __restrict__ Bp,
                                                  unsigned short* __restrict__ C,
                                                  int M) {
    constexpr int KA = (MODE == 1) ? D_IN : D_HID;
    constexpr int NCH = KA / 32;
    __shared__ short Bs[2][8192];  // 2 x 16 KB

    int t = threadIdx.x;
    int lane = t & 63, w = t >> 6;
    int wr2 = w >> 1, wc2 = w & 1;
    int ln = lane & 15, q = lane >> 4;
    int bm = blockIdx.x * 128;
    int bn = blockIdx.y * 128;
    int TB = blockIdx.y * 8;

    const char* Abase[2];
    #pragma unroll
    for (int s = 0; s < 2; ++s) {
        int rr = bm + wr2 * 32 + s * 16 + ln;
        rr = (rr < M) ? rr : (M - 1);
        Abase[s] = (const char*)Av + (size_t)rr * KA * ((MODE == 1) ? 4 : 2);
    }

    f32x4 acc[2][4];
    #pragma unroll
    for (int s = 0; s < 2; ++s)
        #pragma unroll
        for (int tt = 0; tt < 4; ++tt) acc[s][tt] = (f32x4){0.f, 0.f, 0.f, 0.f};

    auto stage = [&](int c, int pb) {
        gload_lds16(Bp + (size_t)c * 16384 + (size_t)(TB + w) * 512 + lane * 8,
                    &Bs[pb][w * 512]);
        gload_lds16(Bp + (size_t)c * 16384 + 8192 + (size_t)(TB + w) * 512 + lane * 8,
                    &Bs[pb][4096 + w * 512]);
    };

    stage(0, 0);

    f32x4 cur0[2], cur1[2];
    short8 curb[2];
    #pragma unroll
    for (int s = 0; s < 2; ++s) {
        if (MODE == 1) {
            const float* Af = (const float*)(Abase[s]) + q * 8;
            cur0[s] = *(const f32x4*)Af;
            cur1[s] = *(const f32x4*)(Af + 4);
        } else {
            curb[s] = *(const short8*)((const unsigned short*)(Abase[s]) + q * 8);
        }
    }
    __syncthreads();

    for (int c = 0; c < NCH; ++c) {
        int pb = c & 1;
        bool more = (c + 1 < NCH);
        if (more) stage(c + 1, pb ^ 1);

        f32x4 nxt0[2], nxt1[2];
        short8 nxtb[2];
        if (more) {
            #pragma unroll
            for (int s = 0; s < 2; ++s) {
                if (MODE == 1) {
                    const float* Af = (const float*)(Abase[s]) + (c + 1) * 32 + q * 8;
                    nxt0[s] = *(const f32x4*)Af;
                    nxt1[s] = *(const f32x4*)(Af + 4);
                } else {
                    nxtb[s] = *(const short8*)((const unsigned short*)(Abase[s]) + (c + 1) * 32 + q * 8);
                }
            }
        }

        short8 a_hi[2], a_lo[2];
        #pragma unroll
        for (int s = 0; s < 2; ++s) {
            if (MODE == 1) {
                float vv[8] = {cur0[s][0], cur0[s][1], cur0[s][2], cur0[s][3],
                               cur1[s][0], cur1[s][1], cur1[s][2], cur1[s][3]};
                #pragma unroll
                for (int j = 0; j < 8; ++j) {
                    unsigned short h = f2b(vv[j]);
                    a_hi[s][j] = (short)h;
                    a_lo[s][j] = (short)f2b(vv[j] - b2f(h));
                }
            } else {
                a_hi[s] = curb[s];
            }
        }

        #pragma unroll
        for (int tt = 0; tt < 4; ++tt) {
            const short* bp = &Bs[pb][(size_t)(wc2 * 4 + tt) * 512 + q * 128 + ln * 8];
            short8 bh = *(const short8*)bp;
            short8 bl2 = *(const short8*)(bp + 4096);
            #pragma unroll
            for (int s = 0; s < 2; ++s) {
                acc[s][tt] = __builtin_amdgcn_mfma_f32_16x16x32_bf16(a_hi[s], bh, acc[s][tt], 0, 0, 0);
                if (MODE == 1)
                    acc[s][tt] = __builtin_amdgcn_mfma_f32_16x16x32_bf16(a_lo[s], bh, acc[s][tt], 0, 0, 0);
                acc[s][tt] = __builtin_amdgcn_mfma_f32_16x16x32_bf16(a_hi[s], bl2, acc[s][tt], 0, 0, 0);
            }
        }
        __syncthreads();

        if (more) {
            #pragma unroll
            for (int s = 0; s < 2; ++s) {
                if (MODE == 1) { cur0[s] = nxt0[s]; cur1[s] = nxt1[s]; }
                else           { curb[s] = nxtb[s]; }
            }
        }
    }

    #pragma unroll
    for (int s = 0; s < 2; ++s)
        #pragma unroll
        for (int tt = 0; tt < 4; ++tt)
            #pragma unroll
            for (int r = 0; r < 4; ++r) {
                int row = bm + wr2 * 32 + s * 16 + q * 4 + r;
                if (row < M)
                    C[(size_t)row * 256 + bn + wc2 * 64 + tt * 16 + ln] = f2b(acc[s][tt][r]);
            }
}

// ---------------- MFMA GEMM v4 (layers 2/3, K=256): 128x256 tile (R3: ~45us) ----
// 512 thr = 8 waves (2 row-groups x 4 col-groups). Single A read (vs gemm7's 2x).
template <int MODE>
__global__ __launch_bounds__(512, 4) void k_gemm4(const void* __restrict__ Av,
                                                  const short* __restrict__ Bp,
                                                  unsigned short* __restrict__ C,
                                                  int M) {
    constexpr int KA = (MODE == 1) ? D_IN : D_HID;
    constexpr int NCH = KA / 32;
    __shared__ short Bs[2][16384];  // 2 x 32 KB

    int t = threadIdx.x;
    int lane = t & 63, w = t >> 6;
    int wr = w >> 2, wc = w & 3;
    int ln = lane & 15, q = lane >> 4;
    int bm = blockIdx.x * 128;

    const char* Abase[4];
    #pragma unroll
    for (int s = 0; s < 4; ++s) {
        int rr = bm + wr * 64 + s * 16 + ln;
        rr = (rr < M) ? rr : (M - 1);
        Abase[s] = (const char*)Av + (size_t)rr * KA * ((MODE == 1) ? 4 : 2);
    }

    f32x4 acc[4][4];
    #pragma unroll
    for (int s = 0; s < 4; ++s)
        #pragma unroll
        for (int tt = 0; tt < 4; ++tt) acc[s][tt] = (f32x4){0.f, 0.f, 0.f, 0.f};

    auto stage = [&](int c, int pb) {
        #pragma unroll
        for (int i = 0; i < 4; ++i) {
            int seg = i * 8 + w;
            gload_lds16(Bp + (size_t)c * 16384 + seg * 512 + lane * 8,
                        &Bs[pb][seg * 512]);
        }
    };

    stage(0, 0);
    __syncthreads();

    for (int c = 0; c < NCH; ++c) {
        int pb = c & 1;
        if (c + 1 < NCH) stage(c + 1, pb ^ 1);

        short8 a_hi[4], a_lo[4];
        #pragma unroll
        for (int s = 0; s < 4; ++s) {
            if (MODE == 1) {
                const float* Af = (const float*)(Abase[s]) + c * 32 + q * 8;
                f32x4 v0 = *(const f32x4*)Af;
                f32x4 v1 = *(const f32x4*)(Af + 4);
                float vv[8] = {v0[0], v0[1], v0[2], v0[3], v1[0], v1[1], v1[2], v1[3]};
                #pragma unroll
                for (int j = 0; j < 8; ++j) {
                    unsigned short h = f2b(vv[j]);
                    a_hi[s][j] = (short)h;
                    a_lo[s][j] = (short)f2b(vv[j] - b2f(h));
                }
            } else {
                const unsigned short* Ab = (const unsigned short*)(Abase[s]) + c * 32 + q * 8;
                a_hi[s] = *(const short8*)Ab;
            }
        }

        #pragma unroll
        for (int tt = 0; tt < 4; ++tt) {
            int T = wc * 4 + tt;
            const short* bp = &Bs[pb][(size_t)(T * 4 + q) * 128 + ln * 8];
            short8 bh = *(const short8*)bp;
            short8 bl = *(const short8*)(bp + 8192);
            #pragma unroll
            for (int s = 0; s < 4; ++s) {
                acc[s][tt] = __builtin_amdgcn_mfma_f32_16x16x32_bf16(a_hi[s], bh, acc[s][tt], 0, 0, 0);
                if (MODE == 1)
                    acc[s][tt] = __builtin_amdgcn_mfma_f32_16x16x32_bf16(a_lo[s], bh, acc[s][tt], 0, 0, 0);
                acc[s][tt] = __builtin_amdgcn_mfma_f32_16x16x32_bf16(
                    (MODE == 1) ? a_hi[s] : a_hi[s], bl, acc[s][tt], 0, 0, 0);
            }
        }
        __syncthreads();
    }

    #pragma unroll
    for (int s = 0; s < 4; ++s)
        #pragma unroll
        for (int tt = 0; tt < 4; ++tt)
            #pragma unroll
            for (int r = 0; r < 4; ++r) {
                int row = bm + wr * 64 + s * 16 + q * 4 + r;
                if (row < M)
                    C[(size_t)row * 256 + wc * 64 + tt * 16 + ln] = f2b(acc[s][tt][r]);
            }
}

// ---------------- aggregation: lane-parallel index prefetch + shfl-fed gathers ---
// At the random-gather byte floor (3 structurally different schemes all null).
template <int RELU, int OUTBF>
__global__ __launch_bounds__(256) void k_agg(const unsigned short* __restrict__ hin,
                                             void* __restrict__ hout,
                                             const int* __restrict__ row_ptr,
                                             const int* __restrict__ csr_src,
                                             const float* __restrict__ dinv,
                                             const float* __restrict__ bias, int N) {
    int w = threadIdx.x >> 6;
    int lane = threadIdx.x & 63;
    int row = blockIdx.x * 4 + w;
    if (row >= N) return;
    int half = lane >> 5;
    int hl = lane & 31;
    int c8 = hl * 8;

    int2 se = *(const int2*)&row_ptr[row];
    int s = se.x, e = se.y;

    float di = dinv[row];
    short8 vs = *(const short8*)&hin[(size_t)row * 256 + c8];
    float4 bb0 = *(const float4*)&bias[c8];
    float4 bb1 = *(const float4*)&bias[c8 + 4];

    float acc[8];
    #pragma unroll
    for (int ch = 0; ch < 8; ++ch) acc[ch] = 0.f;

    for (int base = s; base < e; base += 64) {
        int cnt = e - base;
        if (cnt > 64) cnt = 64;
        int gidx = base + lane;
        if (gidx >= e) gidx = e - 1;
        int myu = csr_src[gidx];
        float mydv = dinv[myu];

        int p = 0;
        for (; p + 8 <= cnt; p += 8) {
            int u[4];
            float dv[4];
            short8 v[4];
            #pragma unroll
            for (int qq = 0; qq < 4; ++qq) {
                u[qq]  = __shfl(myu,  p + 2 * qq + half);
                dv[qq] = __shfl(mydv, p + 2 * qq + half);
            }
            #pragma unroll
            for (int qq = 0; qq < 4; ++qq) v[qq] = *(const short8*)&hin[(size_t)u[qq] * 256 + c8];
            #pragma unroll
            for (int qq = 0; qq < 4; ++qq)
                #pragma unroll
                for (int ch = 0; ch < 8; ++ch)
                    acc[ch] += dv[qq] * b2f((unsigned short)v[qq][ch]);
        }
        for (; p + 2 <= cnt; p += 2) {
            int u  = __shfl(myu,  p + half);
            float dv = __shfl(mydv, p + half);
            short8 v = *(const short8*)&hin[(size_t)u * 256 + c8];
            #pragma unroll
            for (int ch = 0; ch < 8; ++ch) acc[ch] += dv * b2f((unsigned short)v[ch]);
        }
        if (p < cnt) {
            int u = __shfl(myu, p);
            float dv = half ? 0.f : __shfl(mydv, p);
            short8 v = *(const short8*)&hin[(size_t)u * 256 + c8];
            #pragma unroll
            for (int ch = 0; ch < 8; ++ch) acc[ch] += dv * b2f((unsigned short)v[ch]);
        }
    }

    #pragma unroll
    for (int ch = 0; ch < 8; ++ch) acc[ch] += __shfl_xor(acc[ch], 32);

    float dii = di * di;
    float r[8];
    #pragma unroll
    for (int ch = 0; ch < 8; ++ch) {
        float b = (ch < 4) ? ((ch == 0) ? bb0.x : (ch == 1) ? bb0.y : (ch == 2) ? bb0.z : bb0.w)
                           : ((ch == 4) ? bb1.x : (ch == 5) ? bb1.y : (ch == 6) ? bb1.z : bb1.w);
        r[ch] = acc[ch] * di + dii * b2f((unsigned short)vs[ch]) + b;
        if (RELU) r[ch] = fmaxf(r[ch], 0.f);
    }

    float r0 = half ? r[4] : r[0];
    float r1 = half ? r[5] : r[1];
    float r2 = half ? r[6] : r[2];
    float r3 = half ? r[7] : r[3];
    int cofs = c8 + half * 4;

    if (OUTBF) {
        ushort4 o;
        o.x = f2b(r0); o.y = f2b(r1); o.z = f2b(r2); o.w = f2b(r3);
        *(ushort4*)((unsigned short*)hout + (size_t)row * 256 + cofs) = o;
    } else {
        *(float4*)((float*)hout + (size_t)row * 256 + cofs) = make_float4(r0, r1, r2, r3);
    }
}

// ---------------- pool ----------------
__global__ __launch_bounds__(256) void k_pool(const float* __restrict__ h,
                                              const int* __restrict__ cnt,
                                              const int* __restrict__ offg,
                                              float* __restrict__ g) {
    int gi = blockIdx.x, slice = blockIdx.y;
    int c = threadIdx.x;
    int start = offg[gi], n = cnt[gi];
    int per = (n + (int)gridDim.y - 1) / (int)gridDim.y;
    int r0 = slice * per;
    int r1 = min(n, r0 + per);
    float acc = 0.f;
    for (int r = r0; r < r1; ++r) acc += h[(size_t)(start + r) * D_HID + c];
    if (r1 > r0) atomicAdd(&g[gi * D_HID + c], acc);
}

// ---------------- head ----------------
__global__ __launch_bounds__(256) void k_final(const float* __restrict__ g,
                                               const int* __restrict__ cnt,
                                               const float* __restrict__ Wl,
                                               const float* __restrict__ bl,
                                               float* __restrict__ out) {
    __shared__ float gs[D_HID];
    int t = threadIdx.x;
    int gi = blockIdx.y;
    int c = blockIdx.x * 256 + t;
    float inv = 1.0f / (float)max(cnt[gi], 1);
    gs[t] = g[gi * D_HID + t] * inv;
    __syncthreads();
    float acc = bl[c];
    #pragma unroll 8
    for (int k = 0; k < D_HID; ++k) acc = fmaf(gs[k], Wl[(size_t)k * D_IN + c], acc);
    out[(size_t)gi * D_IN + c] = acc;
}

// ---------------- launch ----------------

extern "C" void kernel_launch(void* const* d_in, const int* in_sizes, int n_in,
                              void* d_out, int out_size, void* d_ws, size_t ws_size,
                              hipStream_t stream) {
    const float* x     = (const float*)d_in[0];
    const int*   ei    = (const int*)d_in[1];
    const int*   batch = (const int*)d_in[2];
    const float* W1 = (const float*)d_in[3];
    const float* b1 = (const float*)d_in[4];
    const float* W2 = (const float*)d_in[5];
    const float* b2 = (const float*)d_in[6];
    const float* W3 = (const float*)d_in[7];
    const float* b3 = (const float*)d_in[8];
    const float* Wl = (const float*)d_in[9];
    const float* bl = (const float*)d_in[10];
    float* out = (float*)d_out;

    int N = in_sizes[2];
    int E = in_sizes[1] / 2;
    int G = out_size / D_IN;
    const int* srcp = ei;
    const int* dstp = ei + E;

    char* ws = (char*)d_ws;
    size_t o = 0;
    auto alloc = [&](size_t bytes) -> char* {
        char* p = ws + o;
        o += (bytes + 255) & ~(size_t)255;
        return p;
    };
    int*   deg     = (int*)alloc((size_t)N * 4);
    int*   wptr    = (int*)alloc((size_t)N * 4);
    int*   row_ptr = (int*)alloc((size_t)(N + 1) * 4);
    int*   cnt     = (int*)alloc((size_t)G * 4);
    int*   offg    = (int*)alloc((size_t)G * 4);
    int*   csr_src = (int*)alloc((size_t)E * 4);
    float* dinv    = (float*)alloc((size_t)N * 4);
    float* gbuf    = (float*)alloc((size_t)G * D_HID * 4);
    unsigned short* hG  = (unsigned short*)alloc((size_t)N * D_HID * 2); // GEMM out (bf16)
    unsigned short* hA2 = (unsigned short*)alloc((size_t)N * D_HID * 2); // agg out L1/L2 (bf16)
    float* hF      = (float*)alloc((size_t)N * D_HID * 4);               // agg out L3 (fp32)
    short* Bp1     = (short*)alloc((size_t)(D_IN / 32) * 16384 * 2);
    short* Bp2     = (short*)alloc((size_t)(D_HID / 32) * 16384 * 2);
    short* Bp3     = (short*)alloc((size_t)(D_HID / 32) * 16384 * 2);

    hipMemsetAsync(deg, 0, (size_t)N * 4, stream);
    hipMemsetAsync(wptr, 0, (size_t)N * 4, stream);
    hipMemsetAsync(gbuf, 0, (size_t)G * D_HID * 4, stream);

    int gE = (E + 255) / 256;
    int gN = (N + 255) / 256;

    k_count<<<gE, 256, 0, stream>>>(dstp, deg, E);
    k_dinv<<<gN, 256, 0, stream>>>(deg, dinv, N);
    k_scan<<<1, 1024, 0, stream>>>(deg, row_ptr, N);
    k_fill<<<gE, 256, 0, stream>>>(srcp, dstp, row_ptr, wptr, csr_src, E);
    k_bounds<<<1, 64, 0, stream>>>(batch, cnt, offg, N, G);

    k_prep_B<<<D_IN, 256, 0, stream>>>(W1, Bp1, D_IN);
    k_prep_B<<<D_HID, 256, 0, stream>>>(W2, Bp2, D_HID);
    k_prep_B<<<D_HID, 256, 0, stream>>>(W3, Bp3, D_HID);

    dim3 g7_grid((N + 127) / 128, 2);
    int g4_grid = (N + 127) / 128;
    int agg_grid = (N + 3) / 4;

    // layer 1 (fp32 A, 3-term fused) — gemm7 col-split (R9-validated, 139us)
    k_gemm7<1><<<g7_grid, 512, 0, stream>>>(x, Bp1, hG, N);
    k_agg<1, 1><<<agg_grid, 256, 0, stream>>>(hG, hA2, row_ptr, csr_src, dinv, b1, N);
    // layer 2 (bf16 A exact, 2-term) — gemm4 full-width (R3-validated, ~45us)
    k_gemm4<2><<<g4_grid, 512, 0, stream>>>(hA2, Bp2, hG, N);
    k_agg<1, 1><<<agg_grid, 256, 0, stream>>>(hG, hA2, row_ptr, csr_src, dinv, b2, N);
    // layer 3
    k_gemm4<2><<<g4_grid, 512, 0, stream>>>(hA2, Bp3, hG, N);
    k_agg<0, 0><<<agg_grid, 256, 0, stream>>>(hG, hF, row_ptr, csr_src, dinv, b3, N);

    // pool + head
    dim3 pool_grid(G, 8);
    k_pool<<<pool_grid, 256, 0, stream>>>(hF, cnt, offg, gbuf);
    dim3 fin_grid(D_IN / 256, G);
    k_final<<<fin_grid, 256, 0, stream>>>(gbuf, cnt, Wl, bl, out);
}